// Round 17
// baseline (71.150 us; speedup 1.0000x reference)
//
#include <hip/hip_runtime.h>

// LocalL1Loss: out = mean_{n,h,w} min_{7x7 shift} mean_c |in - shifted(tgt, zero-pad)|
// inputs/targets: (16, 3, 512, 512) fp32. Output: scalar fp32.
// R16: BARRIER-FREE wave-independent structure. Each wave owns an 8x64 output
// band + private 6KB LDS region (3ch x 14 rows x 36 dw), stages it itself,
// waits lgkmcnt(0) (wave-local, no __syncthreads), evals. Waves fully desync
// -> stage/eval overlap across waves on a SIMD (kills the barrier convoy,
// the last unfalsified theory for the 4x gap vs issue model).
// Persistent: 512 blocks x 8 waves, 2 tasks/wave (8192 tasks total).

constexpr int N = 16, C = 3, H = 512, W = 512;
constexpr int K = 7;
constexpr int WROWS = 14;                 // staged rows per wave (8 out + 6 halo)
constexpr int SM_D = 36;                  // dwords per row (72 halves)
constexpr int WBUF = C * WROWS * SM_D;    // 1512 dwords = 6048 B per wave
constexpr int BLK = 512;                  // 8 waves
constexpr int NPOS = C * WROWS * 18;      // 756 float4 positions per wave

typedef _Float16 h2 __attribute__((ext_vector_type(2)));
__device__ inline h2 u2h(unsigned u) { return __builtin_bit_cast(h2, u); }
__device__ inline h2 habs2(h2 x) {
    unsigned u = __builtin_bit_cast(unsigned, x) & 0x7fff7fffu;
    return __builtin_bit_cast(h2, u);
}
__device__ inline unsigned pkrtz(float a, float b) {
    return __builtin_bit_cast(unsigned, __builtin_amdgcn_cvt_pkrtz(a, b));
}

__global__ __launch_bounds__(BLK, 4)
void local_l1_kernel(const float* __restrict__ inputs,
                     const float* __restrict__ targets,
                     float* __restrict__ out) {
    __shared__ unsigned sm_u[8 * WBUF];   // 48,384 B -> 2 blocks/CU (grid 512)

    const int tid = threadIdx.x;
    const int wv  = tid >> 6;
    const int l   = tid & 63;
    const int tx  = l & 7;                // strip (8 outputs wide)
    const int tyw = l >> 3;               // row within band (0..7)
    unsigned* wbuf = &sm_u[wv * WBUF];

    // staging walk init (per-thread, reused per task)
    const int rc0 = l / 18;
    const int d40 = l - rc0 * 18;
    const int c0  = rc0 / 14;
    const int r0  = rc0 - c0 * 14;

    float part = 0.0f;
    const int gw = blockIdx.x * 8 + wv;

    #pragma unroll 1
    for (int tt = 0; tt < 2; ++tt) {
        const int t = gw + tt * 4096;
        const int n = t >> 9;
        const int rem = t & 511;
        const int band = rem >> 3;        // 0..63
        const int colb = rem & 7;         // 0..7
        const int hbase = band * 8;
        const int w0 = colb * 64;

        // ---- inputs: 3ch x 8 floats -> packed f16 ----
        const float* ibase = inputs + ((size_t)n * C * H + (size_t)(hbase + tyw)) * W
                           + (w0 + tx * 8);
        h2 ipk[3][4];
        #pragma unroll
        for (int cc = 0; cc < 3; ++cc) {
            float4 a = *reinterpret_cast<const float4*>(ibase + (size_t)cc * H * W);
            float4 b = *reinterpret_cast<const float4*>(ibase + (size_t)cc * H * W + 4);
            ipk[cc][0] = u2h(pkrtz(a.x, a.y));
            ipk[cc][1] = u2h(pkrtz(a.z, a.w));
            ipk[cc][2] = u2h(pkrtz(b.x, b.y));
            ipk[cc][3] = u2h(pkrtz(b.z, b.w));
        }

        // ---- stage this wave's 14 target rows (3ch, cols w0-4..w0+67) ----
        const float* tbase = targets + (size_t)n * C * H * W;
        const bool interior = (band >= 1) && (band <= 62) && (colb >= 1) && (colb <= 6);
        {
            int c = c0, r = r0, d4 = d40;
            const int colbase = w0 - 4;
            #pragma unroll
            for (int g = 0; g < 3; ++g) {
                float4 v[4]; int idx[4]; bool act[4];
                #pragma unroll
                for (int b = 0; b < 4; ++b) {
                    const int it = g * 4 + b;                  // 0..11
                    const bool active = (it < 11) || (l < NPOS - 11 * 64);  // <52
                    act[b] = active;
                    if (active) {
                        const int gr = hbase - 3 + r;
                        if (interior) {
                            v[b] = *reinterpret_cast<const float4*>(
                                tbase + ((size_t)c * H + gr) * W + (colbase + 4 * d4));
                        } else {
                            const int c4 = colbase + 4 * d4;
                            const bool ok = ((unsigned)gr < (unsigned)H)
                                         && (c4 >= 0) && (c4 + 4 <= W);
                            const int grc = gr < 0 ? 0 : (gr > H - 1 ? H - 1 : gr);
                            const int cc4 = c4 < 0 ? 0 : (c4 > W - 4 ? W - 4 : c4);
                            float4 vv = *reinterpret_cast<const float4*>(
                                tbase + ((size_t)c * H + grc) * W + cc4);
                            if (!ok) { vv.x = 0.f; vv.y = 0.f; vv.z = 0.f; vv.w = 0.f; }
                            v[b] = vv;
                        }
                        idx[b] = (c * WROWS + r) * SM_D + 2 * d4;
                    }
                    r += 3; d4 += 10;                          // step 64 = 3*18+10
                    if (d4 >= 18) { d4 -= 18; r += 1; }
                    if (r >= WROWS) { r -= WROWS; c += 1; }
                }
                #pragma unroll
                for (int b = 0; b < 4; ++b)
                    if (act[b]) {
                        uint2 wpk;
                        wpk.x = pkrtz(v[b].x, v[b].y);
                        wpk.y = pkrtz(v[b].z, v[b].w);
                        *reinterpret_cast<uint2*>(&wbuf[idx[b]]) = wpk;
                    }
            }
        }
        // wave-local LDS drain (no cross-wave sharing -> no __syncthreads)
        asm volatile("s_waitcnt lgkmcnt(0)" ::: "memory");

        // ---- eval: 8 outputs/thread, packed pairs, even/odd-dj split ----
        h2 bestA[4], bestB[4];
        #pragma unroll
        for (int p = 0; p < 4; ++p) { bestA[p] = u2h(0x7bff7bffu); bestB[p] = u2h(0x7bff7bffu); }

        #pragma unroll
        for (int di = 0; di < K; ++di) {
            unsigned t2[3][8];
            #pragma unroll
            for (int cc = 0; cc < 3; ++cc) {
                const uint4* q = reinterpret_cast<const uint4*>(
                    &wbuf[(cc * WROWS + (tyw + di)) * SM_D + tx * 4]);
                uint4 lo = q[0], hi = q[1];
                t2[cc][0] = lo.x; t2[cc][1] = lo.y; t2[cc][2] = lo.z; t2[cc][3] = lo.w;
                t2[cc][4] = hi.x; t2[cc][5] = hi.y; t2[cc][6] = hi.z; t2[cc][7] = hi.w;
            }
            unsigned s[3][7];
            #pragma unroll
            for (int cc = 0; cc < 3; ++cc)
                #pragma unroll
                for (int m = 0; m < 7; ++m)
                    s[cc][m] = __builtin_amdgcn_alignbit(t2[cc][m + 1], t2[cc][m], 16);

            #pragma unroll
            for (int dj = 0; dj < K; ++dj) {
                #pragma unroll
                for (int p = 0; p < 4; ++p) {
                    h2 w0h, w1h, w2h;
                    if (dj & 1) {
                        const int m = p + (dj + 1) / 2;
                        w0h = u2h(t2[0][m]); w1h = u2h(t2[1][m]); w2h = u2h(t2[2][m]);
                    } else {
                        const int m = p + dj / 2;
                        w0h = u2h(s[0][m]); w1h = u2h(s[1][m]); w2h = u2h(s[2][m]);
                    }
                    h2 a0 = habs2(ipk[0][p] - w0h);
                    h2 a1 = habs2(ipk[1][p] - w1h);
                    h2 a2 = habs2(ipk[2][p] - w2h);
                    h2 d  = a0 + a1 + a2;
                    if (dj & 1) bestB[p] = __builtin_elementwise_min(bestB[p], d);
                    else        bestA[p] = __builtin_elementwise_min(bestA[p], d);
                }
            }
        }

        #pragma unroll
        for (int p = 0; p < 4; ++p) {
            h2 b = __builtin_elementwise_min(bestA[p], bestB[p]);
            part += (float)b[0] + (float)b[1];
        }
        // next task overwrites this wave's own buffer; wave-internal order
        // guarantees eval reads completed before new ds_writes issue.
    }

    // ---- reduction ----
    #pragma unroll
    for (int off = 32; off > 0; off >>= 1)
        part += __shfl_down(part, off, 64);

    __shared__ float wsum[BLK / 64];
    if (l == 0) wsum[wv] = part;
    __syncthreads();
    if (tid == 0) {
        float total = 0.0f;
        #pragma unroll
        for (int i = 0; i < BLK / 64; ++i) total += wsum[i];
        atomicAdd(out, total * (1.0f / (3.0f * (float)N * (float)H * (float)W)));
    }
}

extern "C" void kernel_launch(void* const* d_in, const int* in_sizes, int n_in,
                              void* d_out, int out_size, void* d_ws, size_t ws_size,
                              hipStream_t stream) {
    const float* inputs  = (const float*)d_in[0];
    const float* targets = (const float*)d_in[1];
    float* out = (float*)d_out;

    (void)hipMemsetAsync(out, 0, sizeof(float), stream);
    local_l1_kernel<<<dim3(512), BLK, 0, stream>>>(inputs, targets, out);
}